// Round 9
// baseline (1421.041 us; speedup 1.0000x reference)
//
#include <hip/hip_runtime.h>
#include <hip/hip_bf16.h>

// ---------------------------------------------------------------------------
// GCN 5-layer forward on MI355X (gfx950).  Round-3 structure (best measured,
// 1294us) with ONE change: layers 0/1 GEMM uses K64-per-barrier single-buffer
// staging (half the barrier pairs, 96 MFMAs per cluster, no extra VGPR).
//   - CSR build (incoming edges per dst)
//   - per layer: split-bf16 MFMA GEMM (fp32 A staged via LDS as split bf16,
//     epilogue g = dinv*h), then CSR aggregation (fp32) with bias + ReLU.
// Padded feature dims: 512, 224, 192, 128, 96, 64.
// ---------------------------------------------------------------------------

typedef float f32x4 __attribute__((ext_vector_type(4)));
typedef short bf16x8 __attribute__((ext_vector_type(8)));
typedef ushort u16x8 __attribute__((ext_vector_type(8)));

static const int GDIMS[6] = {512, 200, 175, 125, 75, 50};

// ---------------- graph preprocessing ----------------

__global__ void zero_kernel(int* __restrict__ p, int n) {
    int i = blockIdx.x * blockDim.x + threadIdx.x;
    for (; i < n; i += gridDim.x * blockDim.x) p[i] = 0;
}

__global__ void hist_kernel(const int* __restrict__ dst, int E, int* __restrict__ deg) {
    int i = blockIdx.x * blockDim.x + threadIdx.x;
    for (; i < E; i += gridDim.x * blockDim.x) atomicAdd(&deg[dst[i]], 1);
}

__global__ __launch_bounds__(1024) void scan_kernel(const int* __restrict__ deg,
                                                    int* __restrict__ rowptr, int N) {
    __shared__ int sums[1024];
    int t = threadIdx.x;
    int chunk = (N + 1023) >> 10;
    int lo = t * chunk;
    int hi = lo + chunk; if (hi > N) hi = N;
    if (lo > N) lo = N;
    int s = 0;
    for (int i = lo; i < hi; ++i) s += deg[i];
    sums[t] = s;
    __syncthreads();
    for (int off = 1; off < 1024; off <<= 1) {
        int v = (t >= off) ? sums[t - off] : 0;
        __syncthreads();
        sums[t] += v;
        __syncthreads();
    }
    int run = (t > 0) ? sums[t - 1] : 0;
    for (int i = lo; i < hi; ++i) { rowptr[i] = run; run += deg[i]; }
    if (t == 1023) rowptr[N] = run;
}

__global__ void dinv_kernel(const int* __restrict__ deg, float* __restrict__ dinv, int N) {
    int i = blockIdx.x * blockDim.x + threadIdx.x;
    for (; i < N; i += gridDim.x * blockDim.x)
        dinv[i] = rsqrtf((float)(deg[i] + 1));  // +1 self loop
}

__global__ void copy_kernel(const int* __restrict__ a, int* __restrict__ b, int n) {
    int i = blockIdx.x * blockDim.x + threadIdx.x;
    for (; i < n; i += gridDim.x * blockDim.x) b[i] = a[i];
}

__global__ void scatter_kernel(const int* __restrict__ src, const int* __restrict__ dst,
                               int E, int* __restrict__ cursor, int* __restrict__ csrc) {
    int i = blockIdx.x * blockDim.x + threadIdx.x;
    for (; i < E; i += gridDim.x * blockDim.x) {
        int d = dst[i];
        int pos = atomicAdd(&cursor[d], 1);
        csrc[pos] = src[i];
    }
}

// ---------------- weight pre-transpose + split ----------------

__global__ void wsplit_kernel(const float* __restrict__ W, int K, int Nout,
                              int Kp, ushort* __restrict__ Whi, ushort* __restrict__ Wlo) {
    int k = blockIdx.x * blockDim.x + threadIdx.x;
    int n = blockIdx.y;
    if (k >= Kp) return;
    float v = (k < K && n < Nout) ? W[(size_t)k * Nout + n] : 0.f;
    __bf16 h = (__bf16)v;
    ushort hb = __builtin_bit_cast(ushort, h);
    float hf = __builtin_bit_cast(float, (unsigned)hb << 16);
    __bf16 l = (__bf16)(v - hf);
    Whi[(size_t)n * Kp + k] = hb;
    Wlo[(size_t)n * Kp + k] = __builtin_bit_cast(ushort, l);
}

// ---------------- MFMA helpers ----------------

__device__ inline f32x4 mfma16(bf16x8 a, bf16x8 b, f32x4 c) {
    return __builtin_amdgcn_mfma_f32_16x16x32_bf16(a, b, c, 0, 0, 0);
}

__device__ inline void split8(f32x4 a0, f32x4 a1, u16x8& hi, u16x8& lo) {
    float af[8] = {a0[0], a0[1], a0[2], a0[3], a1[0], a1[1], a1[2], a1[3]};
#pragma unroll
    for (int e = 0; e < 8; ++e) {
        __bf16 h = (__bf16)af[e];
        ushort hb = __builtin_bit_cast(ushort, h);
        float hf = __builtin_bit_cast(float, (unsigned)hb << 16);
        __bf16 l = (__bf16)(af[e] - hf);
        hi[e] = hb;
        lo[e] = __builtin_bit_cast(ushort, l);
    }
}

// ------------- K64-per-barrier GEMM (layers 0/1; single LDS buffer) -------------
// Stage BM x 64 (fp32 -> split bf16) -> barrier -> 2x48 MFMAs -> barrier.

template<int WM, int WN>
__global__ __launch_bounds__(WM * WN * 64) void gemm_k64(
    const float* __restrict__ A, int lda, int Arows,
    const ushort* __restrict__ Bhi, const ushort* __restrict__ Blo, int Kp,
    const float* __restrict__ dinv, int N,
    float* __restrict__ C, int ldc)
{
    constexpr int BM = WM * 64;
    constexpr int T = WM * WN * 64;
    constexpr int SROW = BM + 2;
    __shared__ ushort Ah[8 * SROW * 8];
    __shared__ ushort Al[8 * SROW * 8];

    const int tid = threadIdx.x;
    const int lane = tid & 63;
    const int wave = tid >> 6;
    const int wm = (WM == 1) ? 0 : (wave % WM);
    const int wn = (WM == 1) ? wave : (wave / WM);
    const int m0 = blockIdx.x * BM;
    const int kg = lane >> 4;
    const int l16 = lane & 15;

    const ushort* bp[4];
#pragma unroll
    for (int fn = 0; fn < 4; ++fn) {
        int n = wn * 64 + fn * 16 + l16;
        bp[fn] = Bhi + (size_t)n * Kp + kg * 8;
    }
    const size_t lo_off = (size_t)(Blo - Bhi);

    f32x4 acc[4][4];
#pragma unroll
    for (int i = 0; i < 4; ++i)
#pragma unroll
        for (int j = 0; j < 4; ++j) acc[i][j] = (f32x4)0.f;

    for (int k0 = 0; k0 < Kp; k0 += 64) {
        // stage BM x 64 cols (8 k-groups of 8) -> LDS split bf16
        for (int j = tid; j < BM * 8; j += T) {
            int row = j >> 3, jq = j & 7;
            int kk = k0 + jq * 8;
            if (kk < Kp) {
                int gr = m0 + row; if (gr > Arows - 1) gr = Arows - 1;
                const float* ap = A + (size_t)gr * lda + kk;
                f32x4 a0 = *(const f32x4*)ap;
                f32x4 a1 = *(const f32x4*)(ap + 4);
                u16x8 hi, lo;
                split8(a0, a1, hi, lo);
                int idx = (jq * SROW + row) * 8;
                *(u16x8*)&Ah[idx] = hi;
                *(u16x8*)&Al[idx] = lo;
            }
        }
        __syncthreads();
#pragma unroll
        for (int s = 0; s < 2; ++s) {
            if (k0 + s * 32 < Kp) {
                bf16x8 bh[4], bl[4], ah[4], al[4];
#pragma unroll
                for (int fn = 0; fn < 4; ++fn) {
                    bh[fn] = *(const bf16x8*)(bp[fn] + k0 + s * 32);
                    bl[fn] = *(const bf16x8*)(bp[fn] + lo_off + k0 + s * 32);
                }
#pragma unroll
                for (int fm = 0; fm < 4; ++fm) {
                    int idx = ((s * 4 + kg) * SROW + wm * 64 + fm * 16 + l16) * 8;
                    ah[fm] = *(const bf16x8*)&Ah[idx];
                    al[fm] = *(const bf16x8*)&Al[idx];
                }
#pragma unroll
                for (int fm = 0; fm < 4; ++fm)
#pragma unroll
                    for (int fn = 0; fn < 4; ++fn) {
                        acc[fm][fn] = mfma16(ah[fm], bh[fn], acc[fm][fn]);
                        acc[fm][fn] = mfma16(ah[fm], bl[fn], acc[fm][fn]);
                        acc[fm][fn] = mfma16(al[fm], bh[fn], acc[fm][fn]);
                    }
            }
        }
        __syncthreads();
    }

#pragma unroll
    for (int fm = 0; fm < 4; ++fm)
#pragma unroll
        for (int fn = 0; fn < 4; ++fn) {
            int col = wn * 64 + fn * 16 + l16;
            if (col < ldc) {
#pragma unroll
                for (int r = 0; r < 4; ++r) {
                    int row = m0 + wm * 64 + fm * 16 + kg * 4 + r;
                    float dv = (row < N) ? dinv[row] : 0.f;
                    C[(size_t)row * ldc + col] = acc[fm][fn][r] * dv;
                }
            }
        }
}

// ---------------- K32 GEMM (layers 2-4, round-3 proven) ----------------

template<int WM, int WN>
__global__ __launch_bounds__(WM * WN * 64) void gemm_t(
    const float* __restrict__ A, int lda, int Arows,
    const ushort* __restrict__ Bhi, const ushort* __restrict__ Blo, int Kp,
    const float* __restrict__ dinv, int N,
    float* __restrict__ C, int ldc)
{
    constexpr int BM = WM * 64;
    constexpr int T = WM * WN * 64;
    constexpr int SROW = BM + 2;
    __shared__ ushort Ah[4 * SROW * 8];
    __shared__ ushort Al[4 * SROW * 8];

    const int tid = threadIdx.x;
    const int lane = tid & 63;
    const int wave = tid >> 6;
    const int wm = (WM == 1) ? 0 : (wave % WM);
    const int wn = (WM == 1) ? wave : (wave / WM);
    const int m0 = blockIdx.x * BM;
    const int kg = lane >> 4;
    const int l16 = lane & 15;

    const ushort* bp[4];
#pragma unroll
    for (int fn = 0; fn < 4; ++fn) {
        int n = wn * 64 + fn * 16 + l16;
        bp[fn] = Bhi + (size_t)n * Kp + kg * 8;
    }
    const size_t lo_off = (size_t)(Blo - Bhi);

    f32x4 acc[4][4];
#pragma unroll
    for (int i = 0; i < 4; ++i)
#pragma unroll
        for (int j = 0; j < 4; ++j) acc[i][j] = (f32x4)0.f;

    for (int k0 = 0; k0 < Kp; k0 += 32) {
        for (int j = tid; j < BM * 4; j += T) {
            int row = j >> 2, jk = j & 3;
            int gr = m0 + row; if (gr > Arows - 1) gr = Arows - 1;
            const float* ap = A + (size_t)gr * lda + k0 + jk * 8;
            f32x4 a0 = *(const f32x4*)ap;
            f32x4 a1 = *(const f32x4*)(ap + 4);
            u16x8 hi, lo;
            split8(a0, a1, hi, lo);
            int idx = (jk * SROW + row) * 8;
            *(u16x8*)&Ah[idx] = hi;
            *(u16x8*)&Al[idx] = lo;
        }
        __syncthreads();
        bf16x8 bh[4], bl[4], ah[4], al[4];
#pragma unroll
        for (int fn = 0; fn < 4; ++fn) {
            bh[fn] = *(const bf16x8*)(bp[fn] + k0);
            bl[fn] = *(const bf16x8*)(bp[fn] + lo_off + k0);
        }
#pragma unroll
        for (int fm = 0; fm < 4; ++fm) {
            int idx = (kg * SROW + wm * 64 + fm * 16 + l16) * 8;
            ah[fm] = *(const bf16x8*)&Ah[idx];
            al[fm] = *(const bf16x8*)&Al[idx];
        }
#pragma unroll
        for (int fm = 0; fm < 4; ++fm)
#pragma unroll
            for (int fn = 0; fn < 4; ++fn) {
                acc[fm][fn] = mfma16(ah[fm], bh[fn], acc[fm][fn]);
                acc[fm][fn] = mfma16(ah[fm], bl[fn], acc[fm][fn]);
                acc[fm][fn] = mfma16(al[fm], bh[fn], acc[fm][fn]);
            }
        __syncthreads();
    }

#pragma unroll
    for (int fm = 0; fm < 4; ++fm)
#pragma unroll
        for (int fn = 0; fn < 4; ++fn) {
            int col = wn * 64 + fn * 16 + l16;
            if (col < ldc) {
#pragma unroll
                for (int r = 0; r < 4; ++r) {
                    int row = m0 + wm * 64 + fm * 16 + kg * 4 + r;
                    float dv = (row < N) ? dinv[row] : 0.f;
                    C[(size_t)row * ldc + col] = acc[fm][fn][r] * dv;
                }
            }
        }
}

// ---------------- CSR aggregation (round-3 proven) ----------------
// out[i][f] = relu( dinv[i]*(g[i][f] + sum_s g[s][f]) + b[f] ), g = dinv*h.

template<int L>
__global__ __launch_bounds__(256) void agg_t(
    const float* __restrict__ g, int ldg, int nd4,
    const int* __restrict__ rowptr, const int* __restrict__ csrc,
    const float* __restrict__ dinv, const float* __restrict__ bias,
    int D, int N, float* __restrict__ out, int ldo, int relu, int fin)
{
    int node = blockIdx.x * (256 / L) + threadIdx.x / L;
    if (node >= N) return;
    int f4 = threadIdx.x & (L - 1);
    if (f4 >= nd4) return;

    const f32x4* g4 = (const f32x4*)g;
    int ld4 = ldg >> 2;
    f32x4 a0 = g4[(size_t)node * ld4 + f4];   // self term
    f32x4 a1 = (f32x4)0.f, a2 = (f32x4)0.f, a3 = (f32x4)0.f;
    int beg = rowptr[node], end = rowptr[node + 1];
    int j = beg;
    for (; j + 3 < end; j += 4) {
        int s0 = csrc[j], s1 = csrc[j + 1], s2 = csrc[j + 2], s3 = csrc[j + 3];
        a0 += g4[(size_t)s0 * ld4 + f4];
        a1 += g4[(size_t)s1 * ld4 + f4];
        a2 += g4[(size_t)s2 * ld4 + f4];
        a3 += g4[(size_t)s3 * ld4 + f4];
    }
    for (; j < end; ++j) a0 += g4[(size_t)csrc[j] * ld4 + f4];

    f32x4 s = (a0 + a1) + (a2 + a3);
    float di = dinv[node];
    if (fin) {
#pragma unroll
        for (int e = 0; e < 4; ++e) {
            int f = f4 * 4 + e;
            if (f < D) out[(size_t)node * ldo + f] = fmaf(di, s[e], bias[f]);
        }
    } else {
        f32x4 v;
#pragma unroll
        for (int e = 0; e < 4; ++e) {
            int f = f4 * 4 + e;
            float val = (f < D) ? fmaf(di, s[e], bias[f]) : 0.f;
            if (relu) val = fmaxf(val, 0.f);
            v[e] = val;
        }
        *(f32x4*)(out + (size_t)node * ldo + f4 * 4) = v;
    }
}

// ---------------- host launcher ----------------

extern "C" void kernel_launch(void* const* d_in, const int* in_sizes, int n_in,
                              void* d_out, int out_size, void* d_ws, size_t ws_size,
                              hipStream_t stream) {
    const float* x = (const float*)d_in[0];
    const int* ei = (const int*)d_in[1];
    int E = in_sizes[1] / 2;
    int N = in_sizes[0] / GDIMS[0];
    int Mp = ((N + 255) / 256) * 256;
    const int* src = ei;
    const int* dst = ei + E;

    const float* W[5];
    const float* bia[5];
    for (int i = 0; i < 5; ++i) {
        W[i] = (const float*)d_in[2 + 2 * i];
        bia[i] = (const float*)d_in[3 + 2 * i];
    }

    char* ws = (char*)d_ws;
    size_t off = 0;
    auto alloc = [&](size_t bytes) -> void* {
        void* p = ws + off;
        off += (bytes + 255) & ~(size_t)255;
        return p;
    };
    int* deg = (int*)alloc((size_t)N * 4);
    int* rowptr = (int*)alloc((size_t)(N + 1) * 4);
    int* cursor = (int*)alloc((size_t)N * 4);
    float* dinv = (float*)alloc((size_t)N * 4);
    int* csrc = (int*)alloc((size_t)E * 4);
    float* buf0 = (float*)alloc((size_t)Mp * 224 * 4);
    float* buf1 = (float*)alloc((size_t)Mp * 224 * 4);
    ushort* Whi[5];
    ushort* Wlo[5];
    int NB[5] = {256, 192, 128, 128, 64};
    int KP[5] = {512, 224, 192, 128, 96};
    for (int l = 0; l < 5; ++l) {
        Whi[l] = (ushort*)alloc((size_t)NB[l] * KP[l] * 2);
        Wlo[l] = (ushort*)alloc((size_t)NB[l] * KP[l] * 2);
    }
    (void)ws_size;

    // graph preprocessing
    zero_kernel<<<1024, 256, 0, stream>>>(deg, N);
    hist_kernel<<<2048, 256, 0, stream>>>(dst, E, deg);
    scan_kernel<<<1, 1024, 0, stream>>>(deg, rowptr, N);
    dinv_kernel<<<512, 256, 0, stream>>>(deg, dinv, N);
    copy_kernel<<<512, 256, 0, stream>>>(rowptr, cursor, N);
    scatter_kernel<<<2048, 256, 0, stream>>>(src, dst, E, cursor, csrc);

    // weight split
    for (int l = 0; l < 5; ++l) {
        dim3 gw((KP[l] + 255) / 256, NB[l]);
        wsplit_kernel<<<gw, 256, 0, stream>>>(W[l], GDIMS[l], GDIMS[l + 1], KP[l],
                                              Whi[l], Wlo[l]);
    }

    // ---- layer 0 ----
    gemm_k64<1, 4><<<Mp / 64, 256, 0, stream>>>(x, 512, N, Whi[0], Wlo[0], 512,
                                                dinv, N, buf0, 224);
    agg_t<64><<<(N + 3) / 4, 256, 0, stream>>>(buf0, 224, 50, rowptr, csrc, dinv,
                                               bia[0], 200, N, buf1, 224, 1, 0);
    // ---- layer 1 ----
    gemm_k64<1, 3><<<Mp / 64, 192, 0, stream>>>(buf1, 224, N, Whi[1], Wlo[1], 224,
                                                dinv, N, buf0, 192);
    agg_t<64><<<(N + 3) / 4, 256, 0, stream>>>(buf0, 192, 44, rowptr, csrc, dinv,
                                               bia[1], 175, N, buf1, 192, 1, 0);
    // ---- layer 2 ----
    gemm_t<2, 2><<<Mp / 128, 256, 0, stream>>>(buf1, 192, N, Whi[2], Wlo[2], 192,
                                               dinv, N, buf0, 128);
    agg_t<32><<<(N + 7) / 8, 256, 0, stream>>>(buf0, 128, 32, rowptr, csrc, dinv,
                                               bia[2], 125, N, buf1, 128, 1, 0);
    // ---- layer 3 ----
    gemm_t<2, 2><<<Mp / 128, 256, 0, stream>>>(buf1, 128, N, Whi[3], Wlo[3], 128,
                                               dinv, N, buf0, 96);
    agg_t<32><<<(N + 7) / 8, 256, 0, stream>>>(buf0, 96, 19, rowptr, csrc, dinv,
                                               bia[3], 75, N, buf1, 96, 1, 0);
    // ---- layer 4 (final, fp32 out) ----
    gemm_t<4, 1><<<Mp / 256, 256, 0, stream>>>(buf1, 96, N, Whi[4], Wlo[4], 96,
                                               dinv, N, buf0, 64);
    agg_t<16><<<(N + 15) / 16, 256, 0, stream>>>(buf0, 64, 13, rowptr, csrc, dinv,
                                                 bia[4], 50, N, (float*)d_out, 50, 0, 1);
    (void)out_size; (void)n_in;
}

// Round 10
// 1354.397 us; speedup vs baseline: 1.0492x; 1.0492x over previous
//
#include <hip/hip_runtime.h>
#include <hip/hip_bf16.h>

// ---------------------------------------------------------------------------
// GCN 5-layer forward on MI355X (gfx950).  Round-3 structure for layer 0 and
// aggregation (best measured) + NEW: layers 1-4 GEMM is LDS-free/barrier-free
// with A (and W) pre-swizzled into MFMA fragment order:
//   idx(row,k) = (((row/64)*KQ + k/8)*4 + (row/16)%4)*128 + (row%16)*8 + k%8
// so each wave fragment load is one 16B/lane vector over fully-dense lines.
// agg emits next-layer A as split bf16 (hi/lo) directly in this layout.
// Padded feature dims: 512, 224, 192, 128, 96, 64.
// ---------------------------------------------------------------------------

typedef float f32x4 __attribute__((ext_vector_type(4)));
typedef short bf16x8 __attribute__((ext_vector_type(8)));
typedef ushort u16x4 __attribute__((ext_vector_type(4)));
typedef ushort u16x8 __attribute__((ext_vector_type(8)));

static const int GDIMS[6] = {512, 200, 175, 125, 75, 50};

// ---------------- graph preprocessing ----------------

__global__ void zero_kernel(int* __restrict__ p, int n) {
    int i = blockIdx.x * blockDim.x + threadIdx.x;
    for (; i < n; i += gridDim.x * blockDim.x) p[i] = 0;
}

__global__ void hist_kernel(const int* __restrict__ dst, int E, int* __restrict__ deg) {
    int i = blockIdx.x * blockDim.x + threadIdx.x;
    for (; i < E; i += gridDim.x * blockDim.x) atomicAdd(&deg[dst[i]], 1);
}

__global__ __launch_bounds__(1024) void scan_kernel(const int* __restrict__ deg,
                                                    int* __restrict__ rowptr, int N) {
    __shared__ int sums[1024];
    int t = threadIdx.x;
    int chunk = (N + 1023) >> 10;
    int lo = t * chunk;
    int hi = lo + chunk; if (hi > N) hi = N;
    if (lo > N) lo = N;
    int s = 0;
    for (int i = lo; i < hi; ++i) s += deg[i];
    sums[t] = s;
    __syncthreads();
    for (int off = 1; off < 1024; off <<= 1) {
        int v = (t >= off) ? sums[t - off] : 0;
        __syncthreads();
        sums[t] += v;
        __syncthreads();
    }
    int run = (t > 0) ? sums[t - 1] : 0;
    for (int i = lo; i < hi; ++i) { rowptr[i] = run; run += deg[i]; }
    if (t == 1023) rowptr[N] = run;
}

__global__ void dinv_kernel(const int* __restrict__ deg, float* __restrict__ dinv, int N) {
    int i = blockIdx.x * blockDim.x + threadIdx.x;
    for (; i < N; i += gridDim.x * blockDim.x)
        dinv[i] = rsqrtf((float)(deg[i] + 1));  // +1 self loop
}

__global__ void copy_kernel(const int* __restrict__ a, int* __restrict__ b, int n) {
    int i = blockIdx.x * blockDim.x + threadIdx.x;
    for (; i < n; i += gridDim.x * blockDim.x) b[i] = a[i];
}

__global__ void scatter_kernel(const int* __restrict__ src, const int* __restrict__ dst,
                               int E, int* __restrict__ cursor, int* __restrict__ csrc) {
    int i = blockIdx.x * blockDim.x + threadIdx.x;
    for (; i < E; i += gridDim.x * blockDim.x) {
        int d = dst[i];
        int pos = atomicAdd(&cursor[d], 1);
        csrc[pos] = src[i];
    }
}

// ---------------- weight pre-transpose + split ----------------

// row-major [n][k] (layer 0 LDS GEMM)
__global__ void wsplit_kernel(const float* __restrict__ W, int K, int Nout,
                              int Kp, ushort* __restrict__ Whi, ushort* __restrict__ Wlo) {
    int k = blockIdx.x * blockDim.x + threadIdx.x;
    int n = blockIdx.y;
    if (k >= Kp) return;
    float v = (k < K && n < Nout) ? W[(size_t)k * Nout + n] : 0.f;
    __bf16 h = (__bf16)v;
    ushort hb = __builtin_bit_cast(ushort, h);
    float hf = __builtin_bit_cast(float, (unsigned)hb << 16);
    __bf16 l = (__bf16)(v - hf);
    Whi[(size_t)n * Kp + k] = hb;
    Wlo[(size_t)n * Kp + k] = __builtin_bit_cast(ushort, l);
}

// fragment-swizzled (layers 1-4 direct-load GEMM)
__global__ void wsplit_sw(const float* __restrict__ W, int K, int Nout,
                          int Kp, ushort* __restrict__ Whi, ushort* __restrict__ Wlo) {
    int k = blockIdx.x * blockDim.x + threadIdx.x;
    int n = blockIdx.y;
    if (k >= Kp) return;
    int KQ = Kp >> 3;
    float v = (k < K && n < Nout) ? W[(size_t)k * Nout + n] : 0.f;
    __bf16 h = (__bf16)v;
    ushort hb = __builtin_bit_cast(ushort, h);
    float hf = __builtin_bit_cast(float, (unsigned)hb << 16);
    __bf16 l = (__bf16)(v - hf);
    int mb = n >> 6, fm = (n >> 4) & 3, l16 = n & 15;
    int kq = k >> 3, ko = k & 7;
    size_t idx = ((((size_t)mb * KQ + kq) * 4 + fm) * 16 + l16) * 8 + ko;
    Whi[idx] = hb;
    Wlo[idx] = __builtin_bit_cast(ushort, l);
}

// ---------------- MFMA helpers ----------------

__device__ inline f32x4 mfma16(bf16x8 a, bf16x8 b, f32x4 c) {
    return __builtin_amdgcn_mfma_f32_16x16x32_bf16(a, b, c, 0, 0, 0);
}

__device__ inline void split8(f32x4 a0, f32x4 a1, u16x8& hi, u16x8& lo) {
    float af[8] = {a0[0], a0[1], a0[2], a0[3], a1[0], a1[1], a1[2], a1[3]};
#pragma unroll
    for (int e = 0; e < 8; ++e) {
        __bf16 h = (__bf16)af[e];
        ushort hb = __builtin_bit_cast(ushort, h);
        float hf = __builtin_bit_cast(float, (unsigned)hb << 16);
        __bf16 l = (__bf16)(af[e] - hf);
        hi[e] = hb;
        lo[e] = __builtin_bit_cast(ushort, l);
    }
}

// ---------------- layer-0 GEMM (fp32 A via LDS split, K32, round-3 proven) ----

template<int WM, int WN>
__global__ __launch_bounds__(WM * WN * 64) void gemm_t(
    const float* __restrict__ A, int lda, int Arows,
    const ushort* __restrict__ Bhi, const ushort* __restrict__ Blo, int Kp,
    const float* __restrict__ dinv, int N,
    float* __restrict__ C, int ldc)
{
    constexpr int BM = WM * 64;
    constexpr int T = WM * WN * 64;
    constexpr int SROW = BM + 2;
    __shared__ ushort Ah[4 * SROW * 8];
    __shared__ ushort Al[4 * SROW * 8];

    const int tid = threadIdx.x;
    const int lane = tid & 63;
    const int wave = tid >> 6;
    const int wm = (WM == 1) ? 0 : (wave % WM);
    const int wn = (WM == 1) ? wave : (wave / WM);
    const int m0 = blockIdx.x * BM;
    const int kg = lane >> 4;
    const int l16 = lane & 15;

    const ushort* bp[4];
#pragma unroll
    for (int fn = 0; fn < 4; ++fn) {
        int n = wn * 64 + fn * 16 + l16;
        bp[fn] = Bhi + (size_t)n * Kp + kg * 8;
    }
    const size_t lo_off = (size_t)(Blo - Bhi);

    f32x4 acc[4][4];
#pragma unroll
    for (int i = 0; i < 4; ++i)
#pragma unroll
        for (int j = 0; j < 4; ++j) acc[i][j] = (f32x4)0.f;

    for (int k0 = 0; k0 < Kp; k0 += 32) {
        for (int j = tid; j < BM * 4; j += T) {
            int row = j >> 2, jk = j & 3;
            int gr = m0 + row; if (gr > Arows - 1) gr = Arows - 1;
            const float* ap = A + (size_t)gr * lda + k0 + jk * 8;
            f32x4 a0 = *(const f32x4*)ap;
            f32x4 a1 = *(const f32x4*)(ap + 4);
            u16x8 hi, lo;
            split8(a0, a1, hi, lo);
            int idx = (jk * SROW + row) * 8;
            *(u16x8*)&Ah[idx] = hi;
            *(u16x8*)&Al[idx] = lo;
        }
        __syncthreads();
        bf16x8 bh[4], bl[4], ah[4], al[4];
#pragma unroll
        for (int fn = 0; fn < 4; ++fn) {
            bh[fn] = *(const bf16x8*)(bp[fn] + k0);
            bl[fn] = *(const bf16x8*)(bp[fn] + lo_off + k0);
        }
#pragma unroll
        for (int fm = 0; fm < 4; ++fm) {
            int idx = (kg * SROW + wm * 64 + fm * 16 + l16) * 8;
            ah[fm] = *(const bf16x8*)&Ah[idx];
            al[fm] = *(const bf16x8*)&Al[idx];
        }
#pragma unroll
        for (int fm = 0; fm < 4; ++fm)
#pragma unroll
            for (int fn = 0; fn < 4; ++fn) {
                acc[fm][fn] = mfma16(ah[fm], bh[fn], acc[fm][fn]);
                acc[fm][fn] = mfma16(ah[fm], bl[fn], acc[fm][fn]);
                acc[fm][fn] = mfma16(al[fm], bh[fn], acc[fm][fn]);
            }
        __syncthreads();
    }

#pragma unroll
    for (int fm = 0; fm < 4; ++fm)
#pragma unroll
        for (int fn = 0; fn < 4; ++fn) {
            int col = wn * 64 + fn * 16 + l16;
            if (col < ldc) {
#pragma unroll
                for (int r = 0; r < 4; ++r) {
                    int row = m0 + wm * 64 + fm * 16 + kg * 4 + r;
                    float dv = (row < N) ? dinv[row] : 0.f;
                    C[(size_t)row * ldc + col] = acc[fm][fn][r] * dv;
                }
            }
        }
}

// ------- layers 1-4 GEMM: swizzled direct-load, no LDS, no barriers -------
// A and B stored split-bf16 in fragment order. Each fragment load = one 16B
// vector per lane covering fully-dense 64B lines. Pad rows hold finite
// garbage (never written); epilogue dinv=0 zeroes them. Pad k-cols hit B=0.

template<int WN>
__global__ __launch_bounds__(WN * 64) void gemm_sw(
    const ushort* __restrict__ Ahi, const ushort* __restrict__ Alo, int KQ, int Kp,
    const ushort* __restrict__ Bhi, const ushort* __restrict__ Blo,
    const float* __restrict__ dinv, int N,
    float* __restrict__ C, int ldc)
{
    const int lane = threadIdx.x & 63;
    const int wn = threadIdx.x >> 6;
    const int m0 = blockIdx.x * 64;
    const int mb = m0 >> 6;
    const int kg = lane >> 4;
    const int l16 = lane & 15;

    const size_t alo = (size_t)(Alo - Ahi);
    const size_t blo = (size_t)(Blo - Bhi);
    const ushort* ap[4];
    const ushort* bp[4];
#pragma unroll
    for (int fm = 0; fm < 4; ++fm)
        ap[fm] = Ahi + ((((size_t)mb * KQ + kg) * 4 + fm) * 16 + l16) * 8;
#pragma unroll
    for (int fn = 0; fn < 4; ++fn)
        bp[fn] = Bhi + ((((size_t)wn * KQ + kg) * 4 + fn) * 16 + l16) * 8;

    f32x4 acc[4][4];
#pragma unroll
    for (int i = 0; i < 4; ++i)
#pragma unroll
        for (int j = 0; j < 4; ++j) acc[i][j] = (f32x4)0.f;

    const int nsteps = Kp >> 5;
    for (int t = 0; t < nsteps; ++t) {
        const size_t off = (size_t)t * 2048;   // 4 kq * 4 fm * 128 ushorts
        bf16x8 ah[4], al4[4], bh[4], bl[4];
#pragma unroll
        for (int fm = 0; fm < 4; ++fm) {
            ah[fm] = *(const bf16x8*)(ap[fm] + off);
            al4[fm] = *(const bf16x8*)(ap[fm] + alo + off);
        }
#pragma unroll
        for (int fn = 0; fn < 4; ++fn) {
            bh[fn] = *(const bf16x8*)(bp[fn] + off);
            bl[fn] = *(const bf16x8*)(bp[fn] + blo + off);
        }
#pragma unroll
        for (int fm = 0; fm < 4; ++fm)
#pragma unroll
            for (int fn = 0; fn < 4; ++fn) {
                acc[fm][fn] = mfma16(ah[fm], bh[fn], acc[fm][fn]);
                acc[fm][fn] = mfma16(ah[fm], bl[fn], acc[fm][fn]);
                acc[fm][fn] = mfma16(al4[fm], bh[fn], acc[fm][fn]);
            }
    }

#pragma unroll
    for (int fm = 0; fm < 4; ++fm)
#pragma unroll
        for (int fn = 0; fn < 4; ++fn) {
            int col = wn * 64 + fn * 16 + l16;
            if (col < ldc) {
#pragma unroll
                for (int r = 0; r < 4; ++r) {
                    int row = m0 + fm * 16 + kg * 4 + r;
                    float dv = (row < N) ? dinv[row] : 0.f;
                    C[(size_t)row * ldc + col] = acc[fm][fn][r] * dv;
                }
            }
        }
}

// ---------------- CSR aggregation (round-3 gather; swizzled emit) ----------------
// out[i][f] = relu( dinv[i]*(g[i][f] + sum_s g[s][f]) + b[f] ), g = dinv*h.
// Non-final layers emit split bf16 hi/lo in fragment-swizzled layout (= next
// GEMM's A).  Final layer writes fp32 d_out.

template<int L>
__global__ __launch_bounds__(256) void agg_sw(
    const float* __restrict__ g, int ldg, int nd4,
    const int* __restrict__ rowptr, const int* __restrict__ csrc,
    const float* __restrict__ dinv, const float* __restrict__ bias,
    int D, int N,
    ushort* __restrict__ Ahi, ushort* __restrict__ Alo, int KQ,
    float* __restrict__ outF, int ldof, int fin)
{
    int node = blockIdx.x * (256 / L) + threadIdx.x / L;
    if (node >= N) return;
    int f4 = threadIdx.x & (L - 1);
    if (f4 >= nd4) return;

    const f32x4* g4 = (const f32x4*)g;
    int ld4 = ldg >> 2;
    f32x4 a0 = g4[(size_t)node * ld4 + f4];   // self term
    f32x4 a1 = (f32x4)0.f, a2 = (f32x4)0.f, a3 = (f32x4)0.f;
    int beg = rowptr[node], end = rowptr[node + 1];
    int j = beg;
    for (; j + 3 < end; j += 4) {
        int s0 = csrc[j], s1 = csrc[j + 1], s2 = csrc[j + 2], s3 = csrc[j + 3];
        a0 += g4[(size_t)s0 * ld4 + f4];
        a1 += g4[(size_t)s1 * ld4 + f4];
        a2 += g4[(size_t)s2 * ld4 + f4];
        a3 += g4[(size_t)s3 * ld4 + f4];
    }
    for (; j < end; ++j) a0 += g4[(size_t)csrc[j] * ld4 + f4];

    f32x4 s = (a0 + a1) + (a2 + a3);
    float di = dinv[node];

    if (fin) {
#pragma unroll
        for (int e = 0; e < 4; ++e) {
            int f = f4 * 4 + e;
            if (f < D) outF[(size_t)node * ldof + f] = fmaf(di, s[e], bias[f]);
        }
    } else {
        u16x4 hv, lv;
#pragma unroll
        for (int e = 0; e < 4; ++e) {
            int f = f4 * 4 + e;
            float val = 0.f;
            if (f < D) val = fmaxf(fmaf(di, s[e], bias[f]), 0.f);
            __bf16 h = (__bf16)val;
            ushort hb = __builtin_bit_cast(ushort, h);
            float hf = __builtin_bit_cast(float, (unsigned)hb << 16);
            __bf16 l = (__bf16)(val - hf);
            hv[e] = hb;
            lv[e] = __builtin_bit_cast(ushort, l);
        }
        int mb = node >> 6, fm = (node >> 4) & 3, l16 = node & 15;
        int kq = f4 >> 1, ko = (f4 & 1) * 4;
        size_t idx = ((((size_t)mb * KQ + kq) * 4 + fm) * 16 + l16) * 8 + ko;
        *(u16x4*)(Ahi + idx) = hv;
        *(u16x4*)(Alo + idx) = lv;
    }
}

// ---------------- host launcher ----------------

extern "C" void kernel_launch(void* const* d_in, const int* in_sizes, int n_in,
                              void* d_out, int out_size, void* d_ws, size_t ws_size,
                              hipStream_t stream) {
    const float* x = (const float*)d_in[0];
    const int* ei = (const int*)d_in[1];
    int E = in_sizes[1] / 2;
    int N = in_sizes[0] / GDIMS[0];
    int Mp = ((N + 255) / 256) * 256;
    const int* src = ei;
    const int* dst = ei + E;

    const float* W[5];
    const float* bia[5];
    for (int i = 0; i < 5; ++i) {
        W[i] = (const float*)d_in[2 + 2 * i];
        bia[i] = (const float*)d_in[3 + 2 * i];
    }

    char* ws = (char*)d_ws;
    size_t off = 0;
    auto alloc = [&](size_t bytes) -> void* {
        void* p = ws + off;
        off += (bytes + 255) & ~(size_t)255;
        return p;
    };
    int* deg = (int*)alloc((size_t)N * 4);
    int* rowptr = (int*)alloc((size_t)(N + 1) * 4);
    int* cursor = (int*)alloc((size_t)N * 4);
    float* dinv = (float*)alloc((size_t)N * 4);
    int* csrc = (int*)alloc((size_t)E * 4);
    float* g = (float*)alloc((size_t)Mp * 224 * 4);
    ushort* Ahi = (ushort*)alloc((size_t)Mp * 224 * 2);
    ushort* Alo = (ushort*)alloc((size_t)Mp * 224 * 2);
    ushort* Whi[5];
    ushort* Wlo[5];
    int NB[5] = {256, 192, 128, 128, 64};
    int KP[5] = {512, 224, 192, 128, 96};
    for (int l = 0; l < 5; ++l) {
        Whi[l] = (ushort*)alloc((size_t)NB[l] * KP[l] * 2);
        Wlo[l] = (ushort*)alloc((size_t)NB[l] * KP[l] * 2);
    }
    (void)ws_size;

    // graph preprocessing
    zero_kernel<<<1024, 256, 0, stream>>>(deg, N);
    hist_kernel<<<2048, 256, 0, stream>>>(dst, E, deg);
    scan_kernel<<<1, 1024, 0, stream>>>(deg, rowptr, N);
    dinv_kernel<<<512, 256, 0, stream>>>(deg, dinv, N);
    copy_kernel<<<512, 256, 0, stream>>>(rowptr, cursor, N);
    scatter_kernel<<<2048, 256, 0, stream>>>(src, dst, E, cursor, csrc);

    // weight split: layer 0 row-major (LDS GEMM), layers 1-4 swizzled
    {
        dim3 gw((KP[0] + 255) / 256, NB[0]);
        wsplit_kernel<<<gw, 256, 0, stream>>>(W[0], GDIMS[0], GDIMS[1], KP[0],
                                              Whi[0], Wlo[0]);
    }
    for (int l = 1; l < 5; ++l) {
        dim3 gw((KP[l] + 255) / 256, NB[l]);
        wsplit_sw<<<gw, 256, 0, stream>>>(W[l], GDIMS[l], GDIMS[l + 1], KP[l],
                                          Whi[l], Wlo[l]);
    }

    // ---- layer 0: LDS GEMM (round-3 proven) + agg -> swizzled A (Kp=224) ----
    gemm_t<1, 4><<<Mp / 64, 256, 0, stream>>>(x, 512, N, Whi[0], Wlo[0], 512,
                                              dinv, N, g, 224);
    agg_sw<64><<<(N + 3) / 4, 256, 0, stream>>>(g, 224, 50, rowptr, csrc, dinv,
                                                bia[0], 200, N, Ahi, Alo, 28,
                                                nullptr, 0, 0);
    // ---- layer 1: direct-load GEMM (A KQ=28) + agg -> swizzled (Kp=192) ----
    gemm_sw<3><<<Mp / 64, 192, 0, stream>>>(Ahi, Alo, 28, 224, Whi[1], Wlo[1],
                                            dinv, N, g, 192);
    agg_sw<64><<<(N + 3) / 4, 256, 0, stream>>>(g, 192, 44, rowptr, csrc, dinv,
                                                bia[1], 175, N, Ahi, Alo, 24,
                                                nullptr, 0, 0);
    // ---- layer 2: (A KQ=24) -> swizzled (Kp=128) ----
    gemm_sw<2><<<Mp / 64, 128, 0, stream>>>(Ahi, Alo, 24, 192, Whi[2], Wlo[2],
                                            dinv, N, g, 128);
    agg_sw<32><<<(N + 7) / 8, 256, 0, stream>>>(g, 128, 32, rowptr, csrc, dinv,
                                                bia[2], 125, N, Ahi, Alo, 16,
                                                nullptr, 0, 0);
    // ---- layer 3: (A KQ=16) -> swizzled (Kp=96) ----
    gemm_sw<2><<<Mp / 64, 128, 0, stream>>>(Ahi, Alo, 16, 128, Whi[3], Wlo[3],
                                            dinv, N, g, 96);
    agg_sw<32><<<(N + 7) / 8, 256, 0, stream>>>(g, 96, 19, rowptr, csrc, dinv,
                                                bia[3], 75, N, Ahi, Alo, 12,
                                                nullptr, 0, 0);
    // ---- layer 4: (A KQ=12) -> final fp32 out ----
    gemm_sw<1><<<Mp / 64, 64, 0, stream>>>(Ahi, Alo, 12, 96, Whi[4], Wlo[4],
                                           dinv, N, g, 64);
    agg_sw<16><<<(N + 15) / 16, 256, 0, stream>>>(g, 64, 13, rowptr, csrc, dinv,
                                                  bia[4], 50, N, nullptr, nullptr, 0,
                                                  (float*)d_out, 50, 1);
    (void)out_size; (void)n_in;
}